// Round 18
// baseline (99.511 us; speedup 1.0000x reference)
//
#include <hip/hip_runtime.h>
#include <hip/hip_bf16.h>

// MeanPooling: out[b,e,d] = (sum_l map[b,e,l]*doc[b,l,d]) / lens[b,e]
// B=16, E=256, L=4096 (=K), D=512. fp32 in/out, bf16 MFMA inside.
//
// R18: 256x128 tile (402MB logical) at 2 blocks/CU with register-FEASIBLE
// staging (R17's NaN: A reg-staging 128 VGPR + 128 AGPR acc > 256 cap).
//  - A: global_load_lds fp32 (ZERO staging regs; R16-verified swizzle), all
//    4 waves x 8 instrs. A' fp32 [256r][128B], row r slot s holds chunk
//    (s-r)&7; frag read slot (2g+h+l15)&7, 2 x b128 + cvt.
//  - B: reg-staged bf16 write-transpose across ALL 4 waves (4 dwordx4/thr =
//    32 VGPR both sets). B' bf16 [128d][64B]: row d quad-slot s holds k-quad
//    o = s ^ 2((d>>2)&3) (even XOR -> b128 read pairs stay ordered); read
//    base (g ^ ((l15>>2)&3))<<4, imm n*1024.
//  - Uniform vmcnt: 12/set (8 gload_lds + 4 dwordx4); depth-2, vmcnt(12);
//    2 barriers/half (gload_lds writes LDS at issue -> post-compute barrier,
//    R16 protocol); clamped tail; drain at exit.
//  - LDS 2 x 40KB = 80KB -> 2 blocks/CU = exactly 160KiB.
//  - Budget: 32 RS + ~30 addr + ~35 frags + 128 AGPR ~= 225 < 256.
//  - Grid 512 = 16b x 4dt x 8ks; XCD swizzle; split-K x8 memset+atomicAdd.

#define NB 16
#define NE 256
#define NL 4096
#define ND 512
#define KSPLIT 8
#define KPW (NL / KSPLIT)   // 512 per block
#define BK 32
#define NT (KPW / BK)       // 16 k-steps
#define BUFS 40960          // buf stride: A' 32KB + B' 8KB

using f32x4  = __attribute__((ext_vector_type(4))) float;
using u32x2  = __attribute__((ext_vector_type(2))) unsigned;
using u32x4  = __attribute__((ext_vector_type(4))) unsigned;
using bf16x8 = __attribute__((ext_vector_type(8))) short;

static __device__ __forceinline__ unsigned bfbits(float x) {
  return (unsigned)__builtin_bit_cast(unsigned short, (__bf16)x);  // RNE
}
static __device__ __forceinline__ unsigned lds_u32(const void* p) {
  return (unsigned)(size_t)(const __attribute__((address_space(3))) void*)p;
}

#define GLOADX4(DST, PTR) \
  asm volatile("global_load_dwordx4 %0, %1, off" : "=v"(DST) : "v"(PTR))
#define DSW64(ADDR, D, OFF) \
  asm volatile("ds_write_b64 %0, %1 offset:" OFF :: "v"(ADDR), "v"(D) : "memory")
#define DSR128(DST, ADDR, OFF) \
  asm volatile("ds_read_b128 %0, %1 offset:" OFF : "=v"(DST) : "v"(ADDR))
#define WAIT_VM(N)   asm volatile("s_waitcnt vmcnt(" #N ")" ::: "memory")
#define WAIT_LGKM()  asm volatile("s_waitcnt lgkmcnt(0)" ::: "memory")
#define WAIT_LGKM1() asm volatile("s_waitcnt lgkmcnt(1)" ::: "memory")
#define SB0()        __builtin_amdgcn_sched_barrier(0)

#define GLDS16(GP, LP)                                                         \
  __builtin_amdgcn_global_load_lds(                                            \
      (const __attribute__((address_space(1))) void*)(GP),                     \
      (__attribute__((address_space(3))) void*)(LP), 16, 0, 0)

// one k-step: 8 x gload_lds (A -> LDS buf at BS) + 4 x dwordx4 (B -> RS)
#define ISSUE(RS, T, BS)                                                       \
  do {                                                                         \
    _Pragma("unroll") for (int i_ = 0; i_ < 8; ++i_)                           \
        GLDS16(srcA[i_] + (size_t)(T) * 128,                                   \
               smem + (BS) + aDstBase + 1024 * i_);                            \
    const float* pb_ = gB + (size_t)(T) * BK * ND;                             \
    GLOADX4(RS[0], pb_);          GLOADX4(RS[1], pb_ + ND);                    \
    GLOADX4(RS[2], pb_ + 2 * ND); GLOADX4(RS[3], pb_ + 3 * ND);                \
  } while (0)

// cvt B regs -> bf16, write-transpose into B' (WB = per-buf base reg)
#define WRITE_B(RS, WB)                                                        \
  do {                                                                         \
    u32x2 w0_, w1_, w2_, w3_;                                                  \
    w0_[0] = bfbits(RS[0][0]) | (bfbits(RS[1][0]) << 16);                      \
    w0_[1] = bfbits(RS[2][0]) | (bfbits(RS[3][0]) << 16);                      \
    w1_[0] = bfbits(RS[0][1]) | (bfbits(RS[1][1]) << 16);                      \
    w1_[1] = bfbits(RS[2][1]) | (bfbits(RS[3][1]) << 16);                      \
    w2_[0] = bfbits(RS[0][2]) | (bfbits(RS[1][2]) << 16);                      \
    w2_[1] = bfbits(RS[2][2]) | (bfbits(RS[3][2]) << 16);                      \
    w3_[0] = bfbits(RS[0][3]) | (bfbits(RS[1][3]) << 16);                      \
    w3_[1] = bfbits(RS[2][3]) | (bfbits(RS[3][3]) << 16);                      \
    DSW64(WB, w0_, "0");   DSW64(WB, w1_, "64");                               \
    DSW64(WB, w2_, "128"); DSW64(WB, w3_, "192");                              \
  } while (0)

// pack two fp32x4 (lo=k 8g..8g+3, hi=k 8g+4..8g+7) into one bf16x8 A-frag
#define PACKA(DST, LO, HI)                                                     \
  do {                                                                         \
    u32x4 pa_;                                                                 \
    pa_[0] = bfbits(LO[0]) | (bfbits(LO[1]) << 16);                            \
    pa_[1] = bfbits(LO[2]) | (bfbits(LO[3]) << 16);                            \
    pa_[2] = bfbits(HI[0]) | (bfbits(HI[1]) << 16);                            \
    pa_[3] = bfbits(HI[2]) | (bfbits(HI[3]) << 16);                            \
    DST = __builtin_bit_cast(bf16x8, pa_);                                     \
  } while (0)

#define MFMA4(N, BF)                                                           \
  do {                                                                         \
    acc[0][N] = __builtin_amdgcn_mfma_f32_16x16x32_bf16(af[0], BF, acc[0][N], 0, 0, 0); \
    acc[1][N] = __builtin_amdgcn_mfma_f32_16x16x32_bf16(af[1], BF, acc[1][N], 0, 0, 0); \
    acc[2][N] = __builtin_amdgcn_mfma_f32_16x16x32_bf16(af[2], BF, acc[2][N], 0, 0, 0); \
    acc[3][N] = __builtin_amdgcn_mfma_f32_16x16x32_bf16(af[3], BF, acc[3][N], 0, 0, 0); \
  } while (0)

// full tile compute from buf: A0/A1 = A-frag bases (h=0/1), BB = B-frag base
#define COMPUTE(A0, A1, BB)                                                    \
  do {                                                                         \
    bf16x8 af[4];                                                              \
    {                                                                          \
      f32x4 lo0_, hi0_, lo1_, hi1_;                                            \
      DSR128(lo0_, A0, "0");    DSR128(hi0_, A1, "0");                         \
      DSR128(lo1_, A0, "2048"); DSR128(hi1_, A1, "2048");                      \
      WAIT_LGKM(); SB0();                                                      \
      PACKA(af[0], lo0_, hi0_); PACKA(af[1], lo1_, hi1_);                      \
      DSR128(lo0_, A0, "4096"); DSR128(hi0_, A1, "4096");                      \
      DSR128(lo1_, A0, "6144"); DSR128(hi1_, A1, "6144");                      \
      WAIT_LGKM(); SB0();                                                      \
      PACKA(af[2], lo0_, hi0_); PACKA(af[3], lo1_, hi1_);                      \
    }                                                                          \
    bf16x8 bf0_, bf1_;                                                         \
    __builtin_amdgcn_s_setprio(1);                                             \
    DSR128(bf0_, BB, "0");                                                     \
    DSR128(bf1_, BB, "1024"); WAIT_LGKM1(); SB0(); MFMA4(0, bf0_);             \
    DSR128(bf0_, BB, "2048"); WAIT_LGKM1(); SB0(); MFMA4(1, bf1_);             \
    DSR128(bf1_, BB, "3072"); WAIT_LGKM1(); SB0(); MFMA4(2, bf0_);             \
    DSR128(bf0_, BB, "4096"); WAIT_LGKM1(); SB0(); MFMA4(3, bf1_);             \
    DSR128(bf1_, BB, "5120"); WAIT_LGKM1(); SB0(); MFMA4(4, bf0_);             \
    DSR128(bf0_, BB, "6144"); WAIT_LGKM1(); SB0(); MFMA4(5, bf1_);             \
    DSR128(bf1_, BB, "7168"); WAIT_LGKM1(); SB0(); MFMA4(6, bf0_);             \
    WAIT_LGKM();              SB0(); MFMA4(7, bf1_);                           \
    __builtin_amdgcn_s_setprio(0);                                             \
    SB0();                                                                     \
  } while (0)

__global__ __launch_bounds__(256, 2) void mp_gemm(const float* __restrict__ doc,
                                                  const float* __restrict__ emap,
                                                  const float* __restrict__ lens,
                                                  float* __restrict__ out) {
  // 2 bufs (stride 40960): A' fp32 [256r][128B] 32KB + B' bf16 [128d][64B] 8KB
  __shared__ char smem[2 * BUFS];   // 80KB -> 2 blocks/CU = 160KiB exactly

  int bid = (int)blockIdx.x;
  // XCD swizzle: XCD x owns logical [64x,64x+63] = 2 whole batches.
  int logical = (bid & 7) * 64 + (bid >> 3);
  int b    = logical >> 5;      // 16 batches
  int rest = logical & 31;
  int dt = rest >> 3;           // d-tile of 128 (4)
  int ks = rest & 7;            // k-split x8; siblings adjacent -> same XCD

  int tid  = (int)threadIdx.x;
  int w    = tid >> 6;          // wave = e-row block (64 rows each)
  int lane = tid & 63;
  int l15  = lane & 15;
  int g    = lane >> 4;

  unsigned ldsb = lds_u32(smem);

  // ---- A staging (gload_lds): wave w stages rows 64w..64w+63, instr i
  // covers rows r0=64w+8i..+7; lane -> row r0+(lane>>3), slot lane&7,
  // content chunk ((lane&7) - r)&7 of the 128B k-slice.
  const char* srcA[8];
#pragma unroll
  for (int i = 0; i < 8; ++i) {
    int r  = 64 * w + 8 * i + (lane >> 3);
    int cg = ((lane & 7) - r) & 7;
    srcA[i] = (const char*)(emap + (size_t)(b * NE + r) * NL + ks * KPW) + cg * 16;
  }
  int aDstBase = 8192 * w;

  // ---- B staging: thread q=tid&31 (d=4q..4q+3), o=tid>>5 (k=4o..4o+3)
  int q = tid & 31, o = tid >> 5;
  const float* gB = doc + ((size_t)b * NL + ks * KPW + 4 * o) * ND + dt * 128 + 4 * q;
  // B' write: row d=4q+j (imm j*64), quad-slot o^(2*(q&3)) -> byte <<3
  unsigned wB0 = ldsb + 32768 + 4 * q * 64 + (((o ^ (2 * (q & 3))) & 7) << 3);
  unsigned wB1 = wB0 + BUFS;

  // ---- fragment read bases ----
  // A frag m (row 64w+16m+l15; imm m*2048): slot (2g+h+l15)&7
  unsigned arow = (unsigned)((64 * w + l15) * 128);
  unsigned aRd0_0 = ldsb + arow + (((2 * g + l15) & 7) << 4);
  unsigned aRd1_0 = ldsb + arow + (((2 * g + 1 + l15) & 7) << 4);
  unsigned aRd0_1 = aRd0_0 + BUFS;
  unsigned aRd1_1 = aRd1_0 + BUFS;
  // B frag n (d=16n+l15; imm n*1024): slot-pair base (g ^ ((l15>>2)&3))<<4
  unsigned bRd_0 = ldsb + 32768 + l15 * 64 + (((g ^ (l15 >> 2)) & 3) << 4);
  unsigned bRd_1 = bRd_0 + BUFS;

  f32x4 acc[4][8] = {};
  f32x4 RS0[4], RS1[4];

  // prologue: set0 -> buf0, set1 -> buf1; write B of tile0
  ISSUE(RS0, 0, 0);
  SB0();
  ISSUE(RS1, 1, BUFS);
  SB0();
  WAIT_VM(12);                 // set0's 12 vmem landed
  SB0();
  WRITE_B(RS0, wB0);

#pragma unroll 1
  for (int t = 0; t < NT; t += 2) {
    int p2 = t + 2 < NT ? t + 2 : NT - 1;  // clamped (tail-safe; dups benign)
    int p3 = t + 3 < NT ? t + 3 : NT - 1;
    // even: consume buf0 (tile t); refill buf0 <- t+2; B(t+1) -> buf1
    WAIT_LGKM();                       // my B-writes to buf0 done
    __builtin_amdgcn_s_barrier();      // buf0 complete across waves
    SB0();
    COMPUTE(aRd0_0, aRd1_0, bRd_0);
    __builtin_amdgcn_s_barrier();      // all waves done reading buf0
    SB0();
    ISSUE(RS0, p2, 0);
    SB0();
    WAIT_VM(12);                       // set t+1 landed (t+2 in flight)
    SB0();
    WRITE_B(RS1, wB1);
    // odd: consume buf1 (tile t+1); refill buf1 <- t+3; B(t+2) -> buf0
    WAIT_LGKM();
    __builtin_amdgcn_s_barrier();
    SB0();
    COMPUTE(aRd0_1, aRd1_1, bRd_1);
    __builtin_amdgcn_s_barrier();
    SB0();
    ISSUE(RS1, p3, BUFS);
    SB0();
    WAIT_VM(12);
    SB0();
    WRITE_B(RS0, wB0);
  }

  WAIT_VM(0);   // drain dangling clamped prefetches
  SB0();

  // epilogue: divide by lens, atomic-accumulate the k-split partial.
  // C/D frag: row = 64w + 16m + 4g + i, col = dt*128 + 16n + l15.
  const float* lb = lens + b * NE + 64 * w;
  float* ob = out + (size_t)(b * NE + 64 * w) * ND + dt * 128;
#pragma unroll
  for (int m = 0; m < 4; ++m) {
#pragma unroll
    for (int i = 0; i < 4; ++i) {
      int row = 16 * m + 4 * g + i;
      float inv = 1.0f / lb[row];
#pragma unroll
      for (int n = 0; n < 8; ++n)
        unsafeAtomicAdd(&ob[(size_t)row * ND + 16 * n + l15], acc[m][n][i] * inv);
    }
  }
}

extern "C" void kernel_launch(void* const* d_in, const int* in_sizes, int n_in,
                              void* d_out, int out_size, void* d_ws, size_t ws_size,
                              hipStream_t stream) {
  const float* doc  = (const float*)d_in[0];  // (B, L, D)
  const float* emap = (const float*)d_in[1];  // (B, E, L)
  const float* lens = (const float*)d_in[2];  // (B, E)
  float* out = (float*)d_out;                 // (B, E, D)
  hipMemsetAsync(out, 0, (size_t)NB * NE * ND * sizeof(float), stream);
  hipLaunchKernelGGL(mp_gemm, dim3(512), dim3(256), 0, stream, doc, emap, lens, out);
}